// Round 7
// baseline (2374.580 us; speedup 1.0000x reference)
//
#include <hip/hip_runtime.h>
#include <cstdint>
#include <cstddef>

// Problem constants (match reference setup_inputs)
#define NPTS 16384   // N
#define NSAMP 1024   // SAMPLES
#define KNBR 32      // MAX_NEIGHBORS
#define NCH 128      // C

// ---------------------------------------------------------------------------
// ROUND-10 THEORY: R6 proved the fps overhead is LLVM REMATERIALIZATION of
// invariant global loads (VGPR=52 of a 128 budget at 1024thr; ~22 inst/pt
// issued vs 12 in source; waves_per_eu can't fix a remat decision). Fix:
// make coords NON-REMATERIALIZABLE by passing them through opaque
// asm volatile("" : "+v"(x)) after the load -- an asm result can't be
// duplicated, so the allocator must keep it resident (budget 128 >= ~105
// needed; M is loop-carried and inherently non-remat). On top: R4-validated
// inline v_pk_add/mul_f32 (absmax-0-proven) halves the distance math to
// 8 inst/pair.
//
// group (R6 ~125us, 6x off its ~21us traffic floor): serial 64-pt ballot
// scan (~25 dependent chunks) -> 256-pt super-chunks, all 4 waves test in
// parallel, per-wave ballots through LDS, positions via wave-ordered
// popcount prefix. Exact first-K-by-index semantics preserved.
//
// Exactness contract (absmax 0): d = (dx*dx+dy*dy)+dz*dz with contract(off);
// pk ops are elementwise IEEE (sub == add with neg_lo/neg_hi modifier);
// md = fminf(md, d). Argmax tie-break smallest global index: p = slot*1024+t,
// bi = (slot<<10)|t == p; in-pair strict > picks .x (smaller slot) on ties;
// running strict > keeps earlier pair; cross-lane/wave via u64 key
// (f32bits(val)<<32)|~bi -- min-dists >= 0 so f32 bits are u32-monotone,
// ~bi makes larger key == smaller index on value ties.
// ---------------------------------------------------------------------------

#define FPS_TPB 1024
#define FPS_WAVES (FPS_TPB / 64)   // 16

typedef float f32x2 __attribute__((ext_vector_type(2)));

#define PR8_FOREACH(X) X(0) X(1) X(2) X(3) X(4) X(5) X(6) X(7)

__global__ __launch_bounds__(FPS_TPB)
void fps_kernel(
    const float* __restrict__ xyz, float* __restrict__ centroids) {
#pragma clang fp contract(off)
  const int b = blockIdx.x;
  const int t = threadIdx.x;          // 0..1023
  const int lane = t & 63;
  const int wave = t >> 6;            // 0..15
  const float* __restrict__ px = xyz + (size_t)b * NPTS * 3;

#define DECL_PR(j) f32x2 X##j, Y##j, Z##j, M##j;
  PR8_FOREACH(DECL_PR)
#undef DECL_PR

  // pair j covers slots (2j, 2j+1); point p = slot*1024 + t (coalesced)
#define LOAD_PR(j)                                  \
  {                                                 \
    const int pa = (2 * (j)) * FPS_TPB + t;         \
    const int pb = pa + FPS_TPB;                    \
    X##j.x = px[pa * 3 + 0];                        \
    Y##j.x = px[pa * 3 + 1];                        \
    Z##j.x = px[pa * 3 + 2];                        \
    X##j.y = px[pb * 3 + 0];                        \
    Y##j.y = px[pb * 3 + 1];                        \
    Z##j.y = px[pb * 3 + 2];                        \
    M##j = {1e10f, 1e10f};                          \
  }
  PR8_FOREACH(LOAD_PR)
#undef LOAD_PR

  // RESIDENCY PIN: opaque asm results cannot be rematerialized -> the
  // allocator must keep all 24 coord f32x2 (48 VGPRs) register-resident.
  asm volatile("" : "+v"(X0), "+v"(Y0), "+v"(Z0), "+v"(X1), "+v"(Y1),
                    "+v"(Z1), "+v"(X2), "+v"(Y2), "+v"(Z2));
  asm volatile("" : "+v"(X3), "+v"(Y3), "+v"(Z3), "+v"(X4), "+v"(Y4),
                    "+v"(Z4), "+v"(X5), "+v"(Y5), "+v"(Z5));
  asm volatile("" : "+v"(X6), "+v"(Y6), "+v"(Z6), "+v"(X7), "+v"(Y7),
                    "+v"(Z7));

  __shared__ unsigned long long s_wkey[2][FPS_WAVES];  // parity dbuf

  float* co = centroids + (size_t)b * NSAMP * 3;
  float lx = px[0], ly = px[1], lz = px[2];
  if (t == 0) { co[0] = lx; co[1] = ly; co[2] = lz; }

  for (int s = 1; s < NSAMP; ++s) {
    const int par = s & 1;
    const f32x2 cx = {lx, lx};
    const f32x2 cy = {ly, ly};
    const f32x2 cz = {lz, lz};

    float bv = -1.0f;
    int bs = 0;  // best slot 0..15 (compile-time consts feed cndmask)
    // pk math (R4-validated bit-exact): sub via neg_lo/neg_hi, square, sum
    // in source order (dx*dx+dy*dy)+dz*dz, NO fma.
#define UPD_PR(j)                                                         \
    {                                                                     \
      f32x2 dx, dy, dz, sx, sy, sz, s1, s2;                               \
      asm("v_pk_add_f32 %0, %1, %2 neg_lo:[0,1] neg_hi:[0,1]"             \
          : "=v"(dx) : "v"(X##j), "v"(cx));                               \
      asm("v_pk_add_f32 %0, %1, %2 neg_lo:[0,1] neg_hi:[0,1]"             \
          : "=v"(dy) : "v"(Y##j), "v"(cy));                               \
      asm("v_pk_add_f32 %0, %1, %2 neg_lo:[0,1] neg_hi:[0,1]"             \
          : "=v"(dz) : "v"(Z##j), "v"(cz));                               \
      asm("v_pk_mul_f32 %0, %1, %1" : "=v"(sx) : "v"(dx));                \
      asm("v_pk_mul_f32 %0, %1, %1" : "=v"(sy) : "v"(dy));                \
      asm("v_pk_mul_f32 %0, %1, %1" : "=v"(sz) : "v"(dz));                \
      asm("v_pk_add_f32 %0, %1, %2" : "=v"(s1) : "v"(sx), "v"(sy));       \
      asm("v_pk_add_f32 %0, %1, %2" : "=v"(s2) : "v"(s1), "v"(sz));       \
      M##j.x = fminf(M##j.x, s2.x);                                       \
      M##j.y = fminf(M##j.y, s2.y);                                       \
      float vj; int sj;                                                   \
      if (M##j.y > M##j.x) { vj = M##j.y; sj = 2 * (j) + 1; }             \
      else                 { vj = M##j.x; sj = 2 * (j); }                 \
      if (vj > bv) { bv = vj; bs = sj; }  /* strict >: min index */       \
    }
    PR8_FOREACH(UPD_PR)
#undef UPD_PR

    const unsigned int bi = ((unsigned int)bs << 10) | (unsigned int)t;
    unsigned long long key =
        ((unsigned long long)__float_as_uint(bv) << 32) |
        (unsigned int)(~bi);

    // intra-wave butterfly max (6 steps over 64 lanes)
#pragma unroll
    for (int off = 1; off < 64; off <<= 1) {
      const unsigned long long ok = __shfl_xor(key, off);
      if (ok > key) key = ok;
    }
    if (lane == 0) s_wkey[par][wave] = key;
    __syncthreads();  // the ONLY barrier per iteration (parity dbuf)

    // cross-wave reduce: each lane reads one of the 16 wave keys, 4-step
    // xor butterfly within each 16-lane group -> all lanes hold block max
    unsigned long long best = s_wkey[par][lane & 15];
#pragma unroll
    for (int off = 1; off < 16; off <<= 1) {
      const unsigned long long ok = __shfl_xor(best, off);
      if (ok > best) best = ok;
    }
    // uniform across block by construction; readfirstlane -> scalar load
    const unsigned int widx = (unsigned int)__builtin_amdgcn_readfirstlane(
        (int)(~(unsigned int)best));

    lx = px[widx * 3 + 0];
    ly = px[widx * 3 + 1];
    lz = px[widx * 3 + 2];
    if (t == 0) {
      co[s * 3 + 0] = lx;
      co[s * 3 + 1] = ly;
      co[s * 3 + 2] = lz;
    }
  }
}

// ---------------------------------------------------------------------------
// Kernel 2: ball query + gather. One block per centroid (4096 blocks).
// SUPER-CHUNK scan: all 4 waves test 256 points at once; per-wave ballots
// through LDS; position = cnt + popcounts of earlier waves (wave order ==
// index order) + prefix popcount within wave. Exact first-K-by-index.
// Then all 4 waves gather 8 feature rows each.
// ---------------------------------------------------------------------------
__global__ __launch_bounds__(256) void group_kernel(
    const float* __restrict__ xyz, const float* __restrict__ feat,
    const float* __restrict__ centroids,
    float* __restrict__ gxyz, float* __restrict__ gfeat) {
#pragma clang fp contract(off)
  const int gw = blockIdx.x;            // == b * NSAMP + s
  const int b = gw >> 10;
  const int tid = threadIdx.x;
  const int wave = tid >> 6;
  const int lane = tid & 63;

  const float* px = xyz + (size_t)b * NPTS * 3;
  const float* pc = centroids + (size_t)gw * 3;
  const float cx = pc[0], cy = pc[1], cz = pc[2];
  // float32(0.04): numpy compares f32 sqd against python-double 0.04 demoted
  // to f32. NOT 0.2f*0.2f (that's a different float, 1 ulp larger).
  const float rr = 0.04f;

  __shared__ int sh_idx[KNBR];
  __shared__ float sh_gx[KNBR * 3];
  __shared__ unsigned long long sh_mask[4];

  int cnt = 0;  // uniform across all 256 threads by construction
  for (int n0 = 0; n0 < NPTS && cnt < KNBR; n0 += 256) {
    const int p = n0 + tid;
    const float xx = px[p * 3 + 0];
    const float yy = px[p * 3 + 1];
    const float zz = px[p * 3 + 2];
    const float dx = xx - cx;
    const float dy = yy - cy;
    const float dz = zz - cz;
    const float d = (dx * dx + dy * dy) + dz * dz;  // contract(off): no FMA
    const bool in = d <= rr;
    const unsigned long long mask = __ballot(in);
    if (lane == 0) sh_mask[wave] = mask;
    __syncthreads();
    const unsigned long long m0 = sh_mask[0];
    const unsigned long long m1 = sh_mask[1];
    const unsigned long long m2 = sh_mask[2];
    const unsigned long long m3 = sh_mask[3];
    // wave order == index order: base for this wave = cnt + earlier waves
    int base = cnt;
    if (wave > 0) base += (int)__popcll(m0);
    if (wave > 1) base += (int)__popcll(m1);
    if (wave > 2) base += (int)__popcll(m2);
    const int pos = base + (int)__popcll(mask & ((1ull << lane) - 1ull));
    if (in && pos < KNBR) {
      sh_idx[pos] = p;
      sh_gx[pos * 3 + 0] = dx;
      sh_gx[pos * 3 + 1] = dy;
      sh_gx[pos * 3 + 2] = dz;
    }
    cnt += (int)(__popcll(m0) + __popcll(m1) + __popcll(m2) + __popcll(m3));
    __syncthreads();  // protect sh_mask reuse next super-chunk
  }
  // Safety: cannot happen (centroid is itself in-ball), but avoid garbage
  // indices if it somehow does.
  if (cnt == 0 && tid == 0) {
    sh_idx[0] = 0;
    sh_gx[0] = px[0] - cx;
    sh_gx[1] = px[1] - cy;
    sh_gx[2] = px[2] - cz;
  }
  __syncthreads();

  // pad slots [nf, K) with the first hit (matches reference padding)
  const int nf0 = (cnt < 1) ? 1 : cnt;
  const int nf = (nf0 < KNBR) ? nf0 : KNBR;
  if (tid < KNBR && tid >= nf) {
    sh_idx[tid] = sh_idx[0];
    sh_gx[tid * 3 + 0] = sh_gx[0];
    sh_gx[tid * 3 + 1] = sh_gx[1];
    sh_gx[tid * 3 + 2] = sh_gx[2];
  }
  __syncthreads();

  // grouped_xyz: 96 floats (threads 0..95, one shot)
  float* ox = gxyz + (size_t)gw * KNBR * 3;
  if (tid < KNBR * 3) ox[tid] = sh_gx[tid];

  // gather features: each wave handles 8 rows; float2/lane = 512B row
  float* og = gfeat + (size_t)gw * KNBR * NCH;
  const float* pf = feat + (size_t)b * NPTS * NCH;
#pragma unroll
  for (int k = wave; k < KNBR; k += 4) {
    const int row = sh_idx[k];
    const float2 v = ((const float2*)(pf + (size_t)row * NCH))[lane];
    ((float2*)(og + (size_t)k * NCH))[lane] = v;
  }
}

extern "C" void kernel_launch(void* const* d_in, const int* in_sizes, int n_in,
                              void* d_out, int out_size, void* d_ws, size_t ws_size,
                              hipStream_t stream) {
  const float* xyz = (const float*)d_in[0];
  const float* feat = (const float*)d_in[1];
  float* out = (float*)d_out;
  const int B = in_sizes[0] / (NPTS * 3);

  float* centroids = out;                                   // [B,S,3]
  float* gxyz = centroids + (size_t)B * NSAMP * 3;          // [B,S,K,3]
  float* gfeat = gxyz + (size_t)B * NSAMP * KNBR * 3;       // [B,S,K,C]

  fps_kernel<<<B, FPS_TPB, 0, stream>>>(xyz, centroids);
  group_kernel<<<B * NSAMP, 256, 0, stream>>>(xyz, feat, centroids, gxyz,
                                              gfeat);
}

// Round 8
// 2132.789 us; speedup vs baseline: 1.1134x; 1.1134x over previous
//
#include <hip/hip_runtime.h>
#include <cstdint>
#include <cstddef>

// Problem constants (match reference setup_inputs)
#define NPTS 16384   // N
#define NSAMP 1024   // SAMPLES
#define KNBR 32      // MAX_NEIGHBORS
#define NCH 128      // C

// ---------------------------------------------------------------------------
// ROUND-11 THEORY: R0-R7 showed the allocator enforces a ~64-96 VGPR cap at
// any setting and remats (R0/R3/R6) or spills (R7, VGPR=48 + scratch) any
// coord state that doesn't fit. Stop fighting it: X,Y coords move to LDS
// (2 x f32x2[8][1024] = 128KB; one ds_read_b64 per pair at base + j*8192 imm
// offset -> zero addr VALU; 8B stride = 2-way bank aliasing = free; in-loop
// barriers make hoisting back to registers illegal). Z + min-dist stay in
// registers (32 VGPR, Z pinned by opaque asm -- now satisfiable: total ~60
// < 64 cap). Index machinery dropped from the reduce: VALUE-only fmax
// butterflies (f32, not u64-keys), index recovered by the rare thread whose
// local max == gmax via descending slot scan + LDS atomicMin of global idx
// (min == smallest index == reference argmax-first tie-break; bit-exact
// because gmax is an fmax over exactly these md values, all >= 0, no NaN).
//
// Exactness contract (absmax 0): d = (dx*dx+dy*dy)+dz*dz, contract(off), no
// FMA; pk asm ops (R4/R7-validated bit-exact in passing runs) elementwise
// IEEE; md = fminf(md, d); argmax = smallest index among bit-equal maxima.
//
// group kernel: R7 super-chunk version (validated absmax 0), unchanged.
// ---------------------------------------------------------------------------

#define FPS_TPB 1024
#define FPS_WAVES (FPS_TPB / 64)   // 16

typedef float f32x2 __attribute__((ext_vector_type(2)));

#define PR8_FOREACH(X) X(0) X(1) X(2) X(3) X(4) X(5) X(6) X(7)

__global__ __launch_bounds__(FPS_TPB)
void fps_kernel(
    const float* __restrict__ xyz, float* __restrict__ centroids) {
#pragma clang fp contract(off)
  const int b = blockIdx.x;
  const int t = threadIdx.x;          // 0..1023
  const int lane = t & 63;
  const int wave = t >> 6;            // 0..15
  const float* __restrict__ px = xyz + (size_t)b * NPTS * 3;

  // X,Y coordinate home: LDS (128 KB). Entry [j][t] = {coord(p), coord(p')}
  // for p = (2j)*1024 + t, p' = p + 1024. ds_read_b64, offset j*8192.
  __shared__ f32x2 sX[8][FPS_TPB];           // 64 KB
  __shared__ f32x2 sY[8][FPS_TPB];           // 64 KB
  __shared__ float s_wval[2][FPS_WAVES];     // per-wave value max (parity)
  __shared__ unsigned s_widx[2];             // winner global idx (parity)

#define DECL_PR(j) f32x2 Z##j, M##j;
  PR8_FOREACH(DECL_PR)
#undef DECL_PR

#define LOAD_PR(j)                                                        \
  {                                                                       \
    const int pa = (2 * (j)) * FPS_TPB + t;                               \
    const int pb = pa + FPS_TPB;                                          \
    const float xa = px[pa * 3 + 0];                                      \
    const float ya = px[pa * 3 + 1];                                      \
    const float za = px[pa * 3 + 2];                                      \
    const float xb = px[pb * 3 + 0];                                      \
    const float yb = px[pb * 3 + 1];                                      \
    const float zb = px[pb * 3 + 2];                                      \
    sX[j][t] = (f32x2){xa, xb};                                           \
    sY[j][t] = (f32x2){ya, yb};                                           \
    Z##j = (f32x2){za, zb};                                               \
    M##j = (f32x2){1e10f, 1e10f};                                         \
  }
  PR8_FOREACH(LOAD_PR)
#undef LOAD_PR

  // Pin Z: opaque asm results can't be rematerialized; total live state
  // (~60 VGPR) fits the 64-reg cap, so the pin is satisfiable (unlike R7).
  asm volatile("" : "+v"(Z0), "+v"(Z1), "+v"(Z2), "+v"(Z3),
                    "+v"(Z4), "+v"(Z5), "+v"(Z6), "+v"(Z7));

  float* co = centroids + (size_t)b * NSAMP * 3;
  float lx = px[0], ly = px[1], lz = px[2];
  if (t == 0) {
    co[0] = lx; co[1] = ly; co[2] = lz;
    s_widx[0] = 0xFFFFFFFFu;
    s_widx[1] = 0xFFFFFFFFu;
  }
  __syncthreads();  // LDS fill + widx init visible to all

  for (int s = 1; s < NSAMP; ++s) {
    const int par = s & 1;
    const f32x2 cx = {lx, lx};
    const f32x2 cy = {ly, ly};
    const f32x2 cz = {lz, lz};

    // --- update md (pk asm, bit-exact) + thread-local VALUE max ---
    float bv = -1.0f;
#define UPD_PR(j)                                                         \
    {                                                                     \
      const f32x2 xj = sX[j][t];                                          \
      const f32x2 yj = sY[j][t];                                          \
      f32x2 dx, dy, dz, sx, sy, sz, s1, s2;                               \
      asm("v_pk_add_f32 %0, %1, %2 neg_lo:[0,1] neg_hi:[0,1]"             \
          : "=v"(dx) : "v"(xj), "v"(cx));                                 \
      asm("v_pk_add_f32 %0, %1, %2 neg_lo:[0,1] neg_hi:[0,1]"             \
          : "=v"(dy) : "v"(yj), "v"(cy));                                 \
      asm("v_pk_add_f32 %0, %1, %2 neg_lo:[0,1] neg_hi:[0,1]"             \
          : "=v"(dz) : "v"(Z##j), "v"(cz));                               \
      asm("v_pk_mul_f32 %0, %1, %1" : "=v"(sx) : "v"(dx));                \
      asm("v_pk_mul_f32 %0, %1, %1" : "=v"(sy) : "v"(dy));                \
      asm("v_pk_mul_f32 %0, %1, %1" : "=v"(sz) : "v"(dz));                \
      asm("v_pk_add_f32 %0, %1, %2" : "=v"(s1) : "v"(sx), "v"(sy));       \
      asm("v_pk_add_f32 %0, %1, %2" : "=v"(s2) : "v"(s1), "v"(sz));       \
      M##j.x = fminf(M##j.x, s2.x);                                       \
      M##j.y = fminf(M##j.y, s2.y);                                       \
      bv = fmaxf(bv, fmaxf(M##j.x, M##j.y));                              \
    }
    PR8_FOREACH(UPD_PR)
#undef UPD_PR

    // --- wave butterfly on VALUE (f32, cheap) ---
    float wv = bv;
#pragma unroll
    for (int off = 1; off < 64; off <<= 1)
      wv = fmaxf(wv, __shfl_xor(wv, off));
    if (lane == 0) s_wval[par][wave] = wv;
    __syncthreads();  // (A)

    // --- cross-wave: 16 values, 4-step butterfly -> gmax in every lane ---
    float g = s_wval[par][lane & 15];
#pragma unroll
    for (int off = 1; off < 16; off <<= 1)
      g = fmaxf(g, __shfl_xor(g, off));

    // --- index recovery: only threads whose local max == gmax (usually 1).
    // Descending scan => smallest matching slot; atomicMin => smallest
    // global index among tied threads. Bit-equality is exact (fmax chain).
    if (bv == g) {
      int cs = 0;
#define SCAN_PR(j)                                                        \
      { if (M##j.y == g) cs = 2 * (j) + 1;                                \
        if (M##j.x == g) cs = 2 * (j); }
      SCAN_PR(7) SCAN_PR(6) SCAN_PR(5) SCAN_PR(4)
      SCAN_PR(3) SCAN_PR(2) SCAN_PR(1) SCAN_PR(0)
#undef SCAN_PR
      atomicMin(&s_widx[par], ((unsigned)cs << 10) | (unsigned)t);
    }
    if (t == 0) s_widx[par ^ 1] = 0xFFFFFFFFu;  // reset for next iteration
    __syncthreads();  // (B)

    const unsigned widx = (unsigned)__builtin_amdgcn_readfirstlane(
        (int)s_widx[par]);
    // winner coords: uniform address -> scalar broadcast load (L2-hot)
    lx = px[widx * 3 + 0];
    ly = px[widx * 3 + 1];
    lz = px[widx * 3 + 2];
    if (t == 0) {
      co[s * 3 + 0] = lx;
      co[s * 3 + 1] = ly;
      co[s * 3 + 2] = lz;
    }
  }
}

// ---------------------------------------------------------------------------
// Kernel 2: ball query + gather. One block per centroid (4096 blocks).
// SUPER-CHUNK scan: all 4 waves test 256 points at once; per-wave ballots
// through LDS; position = cnt + popcounts of earlier waves (wave order ==
// index order) + prefix popcount within wave. Exact first-K-by-index.
// Then all 4 waves gather 8 feature rows each. (R7-validated, unchanged.)
// ---------------------------------------------------------------------------
__global__ __launch_bounds__(256) void group_kernel(
    const float* __restrict__ xyz, const float* __restrict__ feat,
    const float* __restrict__ centroids,
    float* __restrict__ gxyz, float* __restrict__ gfeat) {
#pragma clang fp contract(off)
  const int gw = blockIdx.x;            // == b * NSAMP + s
  const int b = gw >> 10;
  const int tid = threadIdx.x;
  const int wave = tid >> 6;
  const int lane = tid & 63;

  const float* px = xyz + (size_t)b * NPTS * 3;
  const float* pc = centroids + (size_t)gw * 3;
  const float cx = pc[0], cy = pc[1], cz = pc[2];
  // float32(0.04): numpy compares f32 sqd against python-double 0.04 demoted
  // to f32. NOT 0.2f*0.2f (that's a different float, 1 ulp larger).
  const float rr = 0.04f;

  __shared__ int sh_idx[KNBR];
  __shared__ float sh_gx[KNBR * 3];
  __shared__ unsigned long long sh_mask[4];

  int cnt = 0;  // uniform across all 256 threads by construction
  for (int n0 = 0; n0 < NPTS && cnt < KNBR; n0 += 256) {
    const int p = n0 + tid;
    const float xx = px[p * 3 + 0];
    const float yy = px[p * 3 + 1];
    const float zz = px[p * 3 + 2];
    const float dx = xx - cx;
    const float dy = yy - cy;
    const float dz = zz - cz;
    const float d = (dx * dx + dy * dy) + dz * dz;  // contract(off): no FMA
    const bool in = d <= rr;
    const unsigned long long mask = __ballot(in);
    if (lane == 0) sh_mask[wave] = mask;
    __syncthreads();
    const unsigned long long m0 = sh_mask[0];
    const unsigned long long m1 = sh_mask[1];
    const unsigned long long m2 = sh_mask[2];
    const unsigned long long m3 = sh_mask[3];
    // wave order == index order: base for this wave = cnt + earlier waves
    int base = cnt;
    if (wave > 0) base += (int)__popcll(m0);
    if (wave > 1) base += (int)__popcll(m1);
    if (wave > 2) base += (int)__popcll(m2);
    const int pos = base + (int)__popcll(mask & ((1ull << lane) - 1ull));
    if (in && pos < KNBR) {
      sh_idx[pos] = p;
      sh_gx[pos * 3 + 0] = dx;
      sh_gx[pos * 3 + 1] = dy;
      sh_gx[pos * 3 + 2] = dz;
    }
    cnt += (int)(__popcll(m0) + __popcll(m1) + __popcll(m2) + __popcll(m3));
    __syncthreads();  // protect sh_mask reuse next super-chunk
  }
  // Safety: cannot happen (centroid is itself in-ball), but avoid garbage
  // indices if it somehow does.
  if (cnt == 0 && tid == 0) {
    sh_idx[0] = 0;
    sh_gx[0] = px[0] - cx;
    sh_gx[1] = px[1] - cy;
    sh_gx[2] = px[2] - cz;
  }
  __syncthreads();

  // pad slots [nf, K) with the first hit (matches reference padding)
  const int nf0 = (cnt < 1) ? 1 : cnt;
  const int nf = (nf0 < KNBR) ? nf0 : KNBR;
  if (tid < KNBR && tid >= nf) {
    sh_idx[tid] = sh_idx[0];
    sh_gx[tid * 3 + 0] = sh_gx[0];
    sh_gx[tid * 3 + 1] = sh_gx[1];
    sh_gx[tid * 3 + 2] = sh_gx[2];
  }
  __syncthreads();

  // grouped_xyz: 96 floats (threads 0..95, one shot)
  float* ox = gxyz + (size_t)gw * KNBR * 3;
  if (tid < KNBR * 3) ox[tid] = sh_gx[tid];

  // gather features: each wave handles 8 rows; float2/lane = 512B row
  float* og = gfeat + (size_t)gw * KNBR * NCH;
  const float* pf = feat + (size_t)b * NPTS * NCH;
#pragma unroll
  for (int k = wave; k < KNBR; k += 4) {
    const int row = sh_idx[k];
    const float2 v = ((const float2*)(pf + (size_t)row * NCH))[lane];
    ((float2*)(og + (size_t)k * NCH))[lane] = v;
  }
}

extern "C" void kernel_launch(void* const* d_in, const int* in_sizes, int n_in,
                              void* d_out, int out_size, void* d_ws, size_t ws_size,
                              hipStream_t stream) {
  const float* xyz = (const float*)d_in[0];
  const float* feat = (const float*)d_in[1];
  float* out = (float*)d_out;
  const int B = in_sizes[0] / (NPTS * 3);

  float* centroids = out;                                   // [B,S,3]
  float* gxyz = centroids + (size_t)B * NSAMP * 3;          // [B,S,K,3]
  float* gfeat = gxyz + (size_t)B * NSAMP * KNBR * 3;       // [B,S,K,C]

  fps_kernel<<<B, FPS_TPB, 0, stream>>>(xyz, centroids);
  group_kernel<<<B * NSAMP, 256, 0, stream>>>(xyz, feat, centroids, gxyz,
                                              gfeat);
}

// Round 9
// 2090.871 us; speedup vs baseline: 1.1357x; 1.0200x over previous
//
#include <hip/hip_runtime.h>
#include <cstdint>
#include <cstddef>

// Problem constants (match reference setup_inputs)
#define NPTS 16384   // N
#define NSAMP 1024   // SAMPLES
#define KNBR 32      // MAX_NEIGHBORS
#define NCH 128      // C

// ---------------------------------------------------------------------------
// ROUND-12 THEORY: 8 rounds bracket the exhaustive-FPS wall (R0 1808 / R3
// 1708 / R6 1875 / R8 2034 us): 16K pts x ~11 ops = ~1400 cyc/iter VALU floor
// on one CU, ~2x implementation tax on top, and multi-CU variants hit the
// ~3400-cyc LLC handshake. Attack N: EXACT lazy pruning. One-time 512-cell
// counting sort (LDS) groups each thread's 16 points spatially; per-thread
// AABB + cached argmax key; per iter skip the whole 16-pt update when
// (dist(c,center)-halfdiag)^2 > max(md) with conservative margins (false
// "update" harmless; margins make false "prune" impossible: hd inflated
// x1.0005+1e-6, threshold bv*1.0001+1e-7 vs ~1e-6 rel fp error). Skipped
// fmin is a provable identity => bit-exact. Sorted order => wave-coherent
// branches => execz-skip of whole waves.
//
// Exactness contract (absmax 0): per-point distance formula unchanged:
// d = (dx*dx+dy*dy)+dz*dz, contract(off), no FMA; md = fminf(md,d) (or
// provably-identity skip); argmax tie-break smallest ORIGINAL index via the
// validated u64 key (f32bits(md)<<32)|~origidx -- sort permutes slots, so
// keys carry original indices explicitly; u64 max => larger ~idx == smaller
// idx on value ties. Winner coords re-read from the ORIGINAL px array.
//
// Register budget vs the observed ~64-VGPR cap at 1024thr: x,y live in LDS
// pair layout (read ONLY in update path); z(16) + md(16) + ids(8 packed u16)
// + aabb(4) + cached key(2) + misc ~= 55 regs. Sort ~30-60us one-time.
// Worst case (pruning never fires) ~= R8 + bound ~= 2100us: bounded.
// ---------------------------------------------------------------------------

#define FPS_TPB 1024
#define NCELL 512

typedef float f32x2 __attribute__((ext_vector_type(2)));

#define PR8_FOREACH(X) X(0) X(1) X(2) X(3) X(4) X(5) X(6) X(7)

__global__ __launch_bounds__(FPS_TPB)
void fps_kernel(const float* __restrict__ xyz, float* __restrict__ centroids) {
#pragma clang fp contract(off)
  const int b = blockIdx.x;
  const int t = threadIdx.x;          // 0..1023
  const int lane = t & 63;
  const int wave = t >> 6;            // 0..15
  const float* __restrict__ px = xyz + (size_t)b * NPTS * 3;

  __shared__ float A1[NPTS];                     // 64KB: pass A z / pass B x
  __shared__ float A2[NPTS];                     // 64KB: pass A id / pass B y
  __shared__ unsigned hist[NCELL];
  __shared__ unsigned sbase[NCELL];
  __shared__ unsigned long long s_wkey[2][16];   // parity dbuf (R6-validated)

  // ================= one-time spatial counting sort =================
  float zsr[16];
  unsigned idsr[16];
  {
    float xr[16], yr[16], zr[16];
    int keys[16], dstv[16];
#pragma unroll
    for (int i = 0; i < 16; ++i) {
      const int p = i * FPS_TPB + t;
      xr[i] = px[p * 3 + 0];
      yr[i] = px[p * 3 + 1];
      zr[i] = px[p * 3 + 2];
      int cx = (int)(xr[i] * 8.0f); cx = cx < 0 ? 0 : (cx > 7 ? 7 : cx);
      int cy = (int)(yr[i] * 8.0f); cy = cy < 0 ? 0 : (cy > 7 ? 7 : cy);
      int cz = (int)(zr[i] * 8.0f); cz = cz < 0 ? 0 : (cz > 7 ? 7 : cz);
      keys[i] = cx | (cy << 3) | (cz << 6);   // 0..511
    }
    if (t < NCELL) hist[t] = 0u;
    __syncthreads();
#pragma unroll
    for (int i = 0; i < 16; ++i) atomicAdd(&hist[keys[i]], 1u);
    __syncthreads();
    if (t < NCELL) sbase[t] = hist[t];
    __syncthreads();
    for (int d = 1; d < NCELL; d <<= 1) {       // Hillis-Steele inclusive
      unsigned v = 0u;
      if (t < NCELL && t >= d) v = sbase[t - d];
      __syncthreads();
      if (t < NCELL) sbase[t] += v;
      __syncthreads();
    }
    if (t < NCELL) sbase[t] -= hist[t];         // exclusive base
    __syncthreads();
    if (t < NCELL) hist[t] = 0u;                // running within-cell offsets
    __syncthreads();
#pragma unroll
    for (int i = 0; i < 16; ++i)
      dstv[i] = (int)(sbase[keys[i]] + atomicAdd(&hist[keys[i]], 1u));
    // pass A: scatter z + original index by sorted slot; read back mine
#pragma unroll
    for (int i = 0; i < 16; ++i) {
      A1[dstv[i]] = zr[i];
      ((unsigned*)A2)[dstv[i]] = (unsigned)(i * FPS_TPB + t);
    }
    __syncthreads();
#pragma unroll
    for (int i = 0; i < 16; ++i) {
      const int u = t * 16 + i;                 // my sorted slots
      zsr[i] = A1[u];
      idsr[i] = ((unsigned*)A2)[u];
    }
    __syncthreads();                            // all reads done before reuse
    // pass B: scatter x,y into pair layout [j][t] f32x2 (stays for the loop)
#pragma unroll
    for (int i = 0; i < 16; ++i) {
      const int u = dstv[i];
      const int fi = ((u & 15) >> 1) * 2048 + (u >> 4) * 2 + (u & 1);
      A1[fi] = xr[i];
      A2[fi] = yr[i];
    }
    __syncthreads();
  }

  // ================= register state (named; ~55 VGPR) =================
#define DECL_PR(j) f32x2 Z##j, M##j; unsigned IDp##j;
  PR8_FOREACH(DECL_PR)
#undef DECL_PR
#define SET_PR(j)                                                     \
  Z##j = (f32x2){zsr[2 * (j)], zsr[2 * (j) + 1]};                     \
  M##j = (f32x2){1e10f, 1e10f};                                       \
  IDp##j = (idsr[2 * (j)] & 0xFFFFu) | (idsr[2 * (j) + 1] << 16);
  PR8_FOREACH(SET_PR)
#undef SET_PR

  // per-thread AABB over my 16 sorted points (x,y via LDS, z in regs)
  float mnx = 1e30f, mxx = -1e30f, mny = 1e30f, mxy = -1e30f,
        mnz = 1e30f, mxz = -1e30f;
#define AABB_PR(j) {                                                  \
    const f32x2 xj = ((const f32x2*)A1)[(j) * 1024 + t];              \
    const f32x2 yj = ((const f32x2*)A2)[(j) * 1024 + t];              \
    mnx = fminf(mnx, fminf(xj.x, xj.y));                              \
    mxx = fmaxf(mxx, fmaxf(xj.x, xj.y));                              \
    mny = fminf(mny, fminf(yj.x, yj.y));                              \
    mxy = fmaxf(mxy, fmaxf(yj.x, yj.y));                              \
    mnz = fminf(mnz, fminf(Z##j.x, Z##j.y));                          \
    mxz = fmaxf(mxz, fmaxf(Z##j.x, Z##j.y)); }
  PR8_FOREACH(AABB_PR)
#undef AABB_PR
  const float acx = (mnx + mxx) * 0.5f;
  const float acy = (mny + mxy) * 0.5f;
  const float acz = (mnz + mxz) * 0.5f;
  const float ex = (mxx - mnx) * 0.5f;
  const float ey = (mxy - mny) * 0.5f;
  const float ez = (mxz - mnz) * 0.5f;
  // inflated half-diagonal: covers AABB/center/sqrt rounding conservatively
  const float hd = sqrtf((ex * ex + ey * ey) + ez * ez) * 1.0005f + 1e-6f;

  float* co = centroids + (size_t)b * NSAMP * 3;
  float lx = px[0], ly = px[1], lz = px[2];
  if (t == 0) { co[0] = lx; co[1] = ly; co[2] = lz; }
  unsigned long long kv = 0ull;  // cached per-lane argmax key
  float bv = 1e10f;              // cached max md (=> first iter always updates)

  for (int s = 1; s < NSAMP; ++s) {
    const int par = s & 1;
    // conservative prune test: skip iff (D - hd)^2 > bv (with margins)
    const float ddx = acx - lx, ddy = acy - ly, ddz = acz - lz;
    const float dc2 = (ddx * ddx + ddy * ddy) + ddz * ddz;
    const float lbv = sqrtf(dc2) - hd;
    const bool upd = !(lbv > 0.0f && lbv * lbv > bv * 1.0001f + 1e-7f);
    if (upd) {
      const f32x2 cx2 = {lx, lx}, cy2 = {ly, ly}, cz2 = {lz, lz};
#define UPD_PR(j) {                                                   \
      const f32x2 xj = ((const f32x2*)A1)[(j) * 1024 + t];            \
      const f32x2 yj = ((const f32x2*)A2)[(j) * 1024 + t];            \
      const f32x2 dx = xj - cx2, dy = yj - cy2, dz = Z##j - cz2;      \
      const f32x2 dd = (dx * dx + dy * dy) + dz * dz; /* no FMA */    \
      M##j.x = fminf(M##j.x, dd.x);                                   \
      M##j.y = fminf(M##j.y, dd.y); }
      PR8_FOREACH(UPD_PR)
#undef UPD_PR
      unsigned long long nk = 0ull;
#define KEY_PR(j) {                                                   \
      const unsigned long long k1 =                                   \
          ((unsigned long long)__float_as_uint(M##j.x) << 32) |       \
          (unsigned)~(IDp##j & 0xFFFFu);                              \
      const unsigned long long k2 =                                   \
          ((unsigned long long)__float_as_uint(M##j.y) << 32) |       \
          (unsigned)~(IDp##j >> 16);                                  \
      if (k1 > nk) nk = k1;                                           \
      if (k2 > nk) nk = k2; }
      PR8_FOREACH(KEY_PR)
#undef KEY_PR
      kv = nk;
      bv = __uint_as_float((unsigned)(kv >> 32));
    }
    // wave butterfly max on u64 key (6 steps; R0/R3/R6-validated pattern)
    unsigned long long k = kv;
#pragma unroll
    for (int off = 1; off < 64; off <<= 1) {
      const unsigned long long ok = __shfl_xor(k, off);
      if (ok > k) k = ok;
    }
    if (lane == 0) s_wkey[par][wave] = k;
    __syncthreads();  // the ONLY barrier per iteration (parity dbuf)
    unsigned long long best = s_wkey[par][lane & 15];
#pragma unroll
    for (int off = 1; off < 16; off <<= 1) {
      const unsigned long long ok = __shfl_xor(best, off);
      if (ok > best) best = ok;
    }
    const unsigned widx = (unsigned)__builtin_amdgcn_readfirstlane(
        (int)(~(unsigned)best));
    // winner coords from ORIGINAL array: uniform -> scalar broadcast load
    lx = px[widx * 3 + 0];
    ly = px[widx * 3 + 1];
    lz = px[widx * 3 + 2];
    if (t == 0) {
      co[s * 3 + 0] = lx;
      co[s * 3 + 1] = ly;
      co[s * 3 + 2] = lz;
    }
  }
}

// ---------------------------------------------------------------------------
// Kernel 2: ball query + gather. One block per centroid (4096 blocks).
// Super-chunk scan (R7/R8-validated, ~99us), unchanged.
// ---------------------------------------------------------------------------
__global__ __launch_bounds__(256) void group_kernel(
    const float* __restrict__ xyz, const float* __restrict__ feat,
    const float* __restrict__ centroids,
    float* __restrict__ gxyz, float* __restrict__ gfeat) {
#pragma clang fp contract(off)
  const int gw = blockIdx.x;            // == b * NSAMP + s
  const int b = gw >> 10;
  const int tid = threadIdx.x;
  const int wave = tid >> 6;
  const int lane = tid & 63;

  const float* px = xyz + (size_t)b * NPTS * 3;
  const float* pc = centroids + (size_t)gw * 3;
  const float cx = pc[0], cy = pc[1], cz = pc[2];
  // float32(0.04): numpy compares f32 sqd against python-double 0.04 demoted
  // to f32. NOT 0.2f*0.2f (that's a different float, 1 ulp larger).
  const float rr = 0.04f;

  __shared__ int sh_idx[KNBR];
  __shared__ float sh_gx[KNBR * 3];
  __shared__ unsigned long long sh_mask[4];

  int cnt = 0;  // uniform across all 256 threads by construction
  for (int n0 = 0; n0 < NPTS && cnt < KNBR; n0 += 256) {
    const int p = n0 + tid;
    const float xx = px[p * 3 + 0];
    const float yy = px[p * 3 + 1];
    const float zz = px[p * 3 + 2];
    const float dx = xx - cx;
    const float dy = yy - cy;
    const float dz = zz - cz;
    const float d = (dx * dx + dy * dy) + dz * dz;  // contract(off): no FMA
    const bool in = d <= rr;
    const unsigned long long mask = __ballot(in);
    if (lane == 0) sh_mask[wave] = mask;
    __syncthreads();
    const unsigned long long m0 = sh_mask[0];
    const unsigned long long m1 = sh_mask[1];
    const unsigned long long m2 = sh_mask[2];
    const unsigned long long m3 = sh_mask[3];
    int base = cnt;
    if (wave > 0) base += (int)__popcll(m0);
    if (wave > 1) base += (int)__popcll(m1);
    if (wave > 2) base += (int)__popcll(m2);
    const int pos = base + (int)__popcll(mask & ((1ull << lane) - 1ull));
    if (in && pos < KNBR) {
      sh_idx[pos] = p;
      sh_gx[pos * 3 + 0] = dx;
      sh_gx[pos * 3 + 1] = dy;
      sh_gx[pos * 3 + 2] = dz;
    }
    cnt += (int)(__popcll(m0) + __popcll(m1) + __popcll(m2) + __popcll(m3));
    __syncthreads();  // protect sh_mask reuse next super-chunk
  }
  if (cnt == 0 && tid == 0) {  // safety: cannot happen
    sh_idx[0] = 0;
    sh_gx[0] = px[0] - cx;
    sh_gx[1] = px[1] - cy;
    sh_gx[2] = px[2] - cz;
  }
  __syncthreads();

  const int nf0 = (cnt < 1) ? 1 : cnt;
  const int nf = (nf0 < KNBR) ? nf0 : KNBR;
  if (tid < KNBR && tid >= nf) {
    sh_idx[tid] = sh_idx[0];
    sh_gx[tid * 3 + 0] = sh_gx[0];
    sh_gx[tid * 3 + 1] = sh_gx[1];
    sh_gx[tid * 3 + 2] = sh_gx[2];
  }
  __syncthreads();

  float* ox = gxyz + (size_t)gw * KNBR * 3;
  if (tid < KNBR * 3) ox[tid] = sh_gx[tid];

  float* og = gfeat + (size_t)gw * KNBR * NCH;
  const float* pf = feat + (size_t)b * NPTS * NCH;
#pragma unroll
  for (int k = wave; k < KNBR; k += 4) {
    const int row = sh_idx[k];
    const float2 v = ((const float2*)(pf + (size_t)row * NCH))[lane];
    ((float2*)(og + (size_t)k * NCH))[lane] = v;
  }
}

extern "C" void kernel_launch(void* const* d_in, const int* in_sizes, int n_in,
                              void* d_out, int out_size, void* d_ws, size_t ws_size,
                              hipStream_t stream) {
  const float* xyz = (const float*)d_in[0];
  const float* feat = (const float*)d_in[1];
  float* out = (float*)d_out;
  const int B = in_sizes[0] / (NPTS * 3);

  float* centroids = out;                                   // [B,S,3]
  float* gxyz = centroids + (size_t)B * NSAMP * 3;          // [B,S,K,3]
  float* gfeat = gxyz + (size_t)B * NSAMP * KNBR * 3;       // [B,S,K,C]

  fps_kernel<<<B, FPS_TPB, 0, stream>>>(xyz, centroids);
  group_kernel<<<B * NSAMP, 256, 0, stream>>>(xyz, feat, centroids, gxyz,
                                              gfeat);
}

// Round 10
// 1527.526 us; speedup vs baseline: 1.5545x; 1.3688x over previous
//
#include <hip/hip_runtime.h>
#include <cstdint>
#include <cstddef>

// Problem constants (match reference setup_inputs)
#define NPTS 16384   // N
#define NSAMP 1024   // SAMPLES
#define KNBR 32      // MAX_NEIGHBORS
#define NCH 128      // C

// ---------------------------------------------------------------------------
// ROUND-13 THEORY: R9's per-LANE prune saved nothing because partially-masked
// VALU still issues full cycles -- only whole-wave execz skips save. Fix the
// granularity: (1) MORTON sort order -> a wave's contiguous 1024 points are a
// compact ~0.5x0.5x0.25 box (lex order gave a full-x slab, skips never fired);
// (2) WAVE-uniform prune using exact per-axis AABB box-distance vs the wave's
// cached max-md (high bits of its cached butterfly key): skip iff
// bd2 > bv_wave*1.00001 -- all inputs lane-invariant => branch uniform =>
// s_cbranch_execz skips update+key+butterfly (~440 cyc) for the whole wave;
// (3) per-thread prune machinery deleted (costs issue, saves none).
//
// Prune safety (bit-exact): bd2 <= true min d^2 to any wave point (exact
// fmin/fmax AABB; sub/mul rounding < 1e-6 rel, margin 1e-5); skip =>
// d^2(p,c) > md[p] for all p => fminf identity => md and hence the wave key
// unchanged => republishing the cached key is exact. False "update" harmless.
//
// Exactness contract (absmax 0), unchanged from validated R9: per-point
// d = (dx*dx+dy*dy)+dz*dz, contract(off), no FMA; md = fminf(md,d); argmax
// tie-break smallest ORIGINAL index via u64 key (f32bits(md)<<32)|~origidx
// (sort permutes slots; keys carry orig indices; md >= 0 so f32 bits are
// u32-monotone; ~idx => larger key == smaller index on ties). Winner coords
// re-read from ORIGINAL px. group_kernel: R7/R8/R9-validated, unchanged.
// ---------------------------------------------------------------------------

#define FPS_TPB 1024
#define NCELL 512

typedef float f32x2 __attribute__((ext_vector_type(2)));

#define PR8_FOREACH(X) X(0) X(1) X(2) X(3) X(4) X(5) X(6) X(7)

__global__ __launch_bounds__(FPS_TPB)
void fps_kernel(const float* __restrict__ xyz, float* __restrict__ centroids) {
#pragma clang fp contract(off)
  const int b = blockIdx.x;
  const int t = threadIdx.x;          // 0..1023
  const int lane = t & 63;
  const int wave = t >> 6;            // 0..15
  const float* __restrict__ px = xyz + (size_t)b * NPTS * 3;

  __shared__ float A1[NPTS];                     // 64KB: pass A z / pass B x
  __shared__ float A2[NPTS];                     // 64KB: pass A id / pass B y
  __shared__ unsigned hist[NCELL];
  __shared__ unsigned sbase[NCELL];
  __shared__ unsigned long long s_wkey[2][16];   // parity dbuf (validated)

  // ================= one-time spatial counting sort (MORTON order) =========
  float zsr[16];
  unsigned idsr[16];
  {
    float xr[16], yr[16], zr[16];
    int keys[16], dstv[16];
#pragma unroll
    for (int i = 0; i < 16; ++i) {
      const int p = i * FPS_TPB + t;
      xr[i] = px[p * 3 + 0];
      yr[i] = px[p * 3 + 1];
      zr[i] = px[p * 3 + 2];
      int cx = (int)(xr[i] * 8.0f); cx = cx < 0 ? 0 : (cx > 7 ? 7 : cx);
      int cy = (int)(yr[i] * 8.0f); cy = cy < 0 ? 0 : (cy > 7 ? 7 : cy);
      int cz = (int)(zr[i] * 8.0f); cz = cz < 0 ? 0 : (cz > 7 ? 7 : cz);
      // Morton interleave (bits 0,3,6 per axis): compact contiguous ranges
      const int mx = (cx & 1) | ((cx & 2) << 2) | ((cx & 4) << 4);
      const int my = (cy & 1) | ((cy & 2) << 2) | ((cy & 4) << 4);
      const int mz = (cz & 1) | ((cz & 2) << 2) | ((cz & 4) << 4);
      keys[i] = mx | (my << 1) | (mz << 2);   // 0..511
    }
    if (t < NCELL) hist[t] = 0u;
    __syncthreads();
#pragma unroll
    for (int i = 0; i < 16; ++i) atomicAdd(&hist[keys[i]], 1u);
    __syncthreads();
    if (t < NCELL) sbase[t] = hist[t];
    __syncthreads();
    for (int d = 1; d < NCELL; d <<= 1) {       // Hillis-Steele inclusive
      unsigned v = 0u;
      if (t < NCELL && t >= d) v = sbase[t - d];
      __syncthreads();
      if (t < NCELL) sbase[t] += v;
      __syncthreads();
    }
    if (t < NCELL) sbase[t] -= hist[t];         // exclusive base
    __syncthreads();
    if (t < NCELL) hist[t] = 0u;                // running within-cell offsets
    __syncthreads();
#pragma unroll
    for (int i = 0; i < 16; ++i)
      dstv[i] = (int)(sbase[keys[i]] + atomicAdd(&hist[keys[i]], 1u));
    // pass A: scatter z + original index by sorted slot; read back mine
#pragma unroll
    for (int i = 0; i < 16; ++i) {
      A1[dstv[i]] = zr[i];
      ((unsigned*)A2)[dstv[i]] = (unsigned)(i * FPS_TPB + t);
    }
    __syncthreads();
#pragma unroll
    for (int i = 0; i < 16; ++i) {
      const int u = t * 16 + i;                 // my sorted slots
      zsr[i] = A1[u];
      idsr[i] = ((unsigned*)A2)[u];
    }
    __syncthreads();                            // all reads done before reuse
    // pass B: scatter x,y into pair layout [j][t] f32x2 (stays for the loop)
#pragma unroll
    for (int i = 0; i < 16; ++i) {
      const int u = dstv[i];
      const int fi = ((u & 15) >> 1) * 2048 + (u >> 4) * 2 + (u & 1);
      A1[fi] = xr[i];
      A2[fi] = yr[i];
    }
    __syncthreads();
  }

  // ================= register state (~60 VGPR) =================
#define DECL_PR(j) f32x2 Z##j, M##j; unsigned IDp##j;
  PR8_FOREACH(DECL_PR)
#undef DECL_PR
#define SET_PR(j)                                                     \
  Z##j = (f32x2){zsr[2 * (j)], zsr[2 * (j) + 1]};                     \
  M##j = (f32x2){1e10f, 1e10f};                                       \
  IDp##j = (idsr[2 * (j)] & 0xFFFFu) | (idsr[2 * (j) + 1] << 16);
  PR8_FOREACH(SET_PR)
#undef SET_PR

  // per-thread exact AABB, then reduce to per-WAVE exact AABB (uniform)
  float mnx = 1e30f, mxx = -1e30f, mny = 1e30f, mxy = -1e30f,
        mnz = 1e30f, mxz = -1e30f;
#define AABB_PR(j) {                                                  \
    const f32x2 xj = ((const f32x2*)A1)[(j) * 1024 + t];              \
    const f32x2 yj = ((const f32x2*)A2)[(j) * 1024 + t];              \
    mnx = fminf(mnx, fminf(xj.x, xj.y));                              \
    mxx = fmaxf(mxx, fmaxf(xj.x, xj.y));                              \
    mny = fminf(mny, fminf(yj.x, yj.y));                              \
    mxy = fmaxf(mxy, fmaxf(yj.x, yj.y));                              \
    mnz = fminf(mnz, fminf(Z##j.x, Z##j.y));                          \
    mxz = fmaxf(mxz, fmaxf(Z##j.x, Z##j.y)); }
  PR8_FOREACH(AABB_PR)
#undef AABB_PR
#pragma unroll
  for (int off = 1; off < 64; off <<= 1) {
    mnx = fminf(mnx, __shfl_xor(mnx, off));
    mxx = fmaxf(mxx, __shfl_xor(mxx, off));
    mny = fminf(mny, __shfl_xor(mny, off));
    mxy = fmaxf(mxy, __shfl_xor(mxy, off));
    mnz = fminf(mnz, __shfl_xor(mnz, off));
    mxz = fmaxf(mxz, __shfl_xor(mxz, off));
  }
  // mnx..mxz now wave-uniform exact bounds over the wave's 1024 points

  float* co = centroids + (size_t)b * NSAMP * 3;
  float lx = px[0], ly = px[1], lz = px[2];
  if (t == 0) { co[0] = lx; co[1] = ly; co[2] = lz; }
  unsigned long long wkc = 0ull;  // wave's cached reduced key (uniform)
  float bvw = 1e10f;              // wave's cached max md (=> 1st iter updates)

  for (int s = 1; s < NSAMP; ++s) {
    const int par = s & 1;
    // wave-uniform exact box distance^2 from centroid to wave AABB
    const float dxb = fmaxf(fmaxf(mnx - lx, lx - mxx), 0.0f);
    const float dyb = fmaxf(fmaxf(mny - ly, ly - mxy), 0.0f);
    const float dzb = fmaxf(fmaxf(mnz - lz, lz - mxz), 0.0f);
    const float bd2 = (dxb * dxb + dyb * dyb) + dzb * dzb;
    unsigned long long wk;
    if (!(bd2 > bvw * 1.00001f)) {   // wave-uniform branch -> execz skip
      const f32x2 cx2 = {lx, lx}, cy2 = {ly, ly}, cz2 = {lz, lz};
#define UPD_PR(j) {                                                   \
      const f32x2 xj = ((const f32x2*)A1)[(j) * 1024 + t];            \
      const f32x2 yj = ((const f32x2*)A2)[(j) * 1024 + t];            \
      const f32x2 dx = xj - cx2, dy = yj - cy2, dz = Z##j - cz2;      \
      const f32x2 dd = (dx * dx + dy * dy) + dz * dz; /* no FMA */    \
      M##j.x = fminf(M##j.x, dd.x);                                   \
      M##j.y = fminf(M##j.y, dd.y); }
      PR8_FOREACH(UPD_PR)
#undef UPD_PR
      unsigned long long nk = 0ull;
#define KEY_PR(j) {                                                   \
      const unsigned long long k1 =                                   \
          ((unsigned long long)__float_as_uint(M##j.x) << 32) |       \
          (unsigned)~(IDp##j & 0xFFFFu);                              \
      const unsigned long long k2 =                                   \
          ((unsigned long long)__float_as_uint(M##j.y) << 32) |       \
          (unsigned)~(IDp##j >> 16);                                  \
      if (k1 > nk) nk = k1;                                           \
      if (k2 > nk) nk = k2; }
      PR8_FOREACH(KEY_PR)
#undef KEY_PR
      // wave butterfly max on u64 key (6 steps; validated pattern)
#pragma unroll
      for (int off = 1; off < 64; off <<= 1) {
        const unsigned long long ok = __shfl_xor(nk, off);
        if (ok > nk) nk = ok;
      }
      wk = nk;
      wkc = nk;
      bvw = __uint_as_float((unsigned)(nk >> 32));
    } else {
      wk = wkc;  // md provably unchanged for every wave point
    }
    if (lane == 0) s_wkey[par][wave] = wk;
    __syncthreads();  // the ONLY barrier per iteration (parity dbuf)
    unsigned long long best = s_wkey[par][lane & 15];
#pragma unroll
    for (int off = 1; off < 16; off <<= 1) {
      const unsigned long long ok = __shfl_xor(best, off);
      if (ok > best) best = ok;
    }
    const unsigned widx = (unsigned)__builtin_amdgcn_readfirstlane(
        (int)(~(unsigned)best));
    // winner coords from ORIGINAL array: uniform -> scalar broadcast load
    lx = px[widx * 3 + 0];
    ly = px[widx * 3 + 1];
    lz = px[widx * 3 + 2];
    if (t == 0) {
      co[s * 3 + 0] = lx;
      co[s * 3 + 1] = ly;
      co[s * 3 + 2] = lz;
    }
  }
}

// ---------------------------------------------------------------------------
// Kernel 2: ball query + gather. One block per centroid (4096 blocks).
// Super-chunk scan (R7/R8/R9-validated, ~100us), unchanged.
// ---------------------------------------------------------------------------
__global__ __launch_bounds__(256) void group_kernel(
    const float* __restrict__ xyz, const float* __restrict__ feat,
    const float* __restrict__ centroids,
    float* __restrict__ gxyz, float* __restrict__ gfeat) {
#pragma clang fp contract(off)
  const int gw = blockIdx.x;            // == b * NSAMP + s
  const int b = gw >> 10;
  const int tid = threadIdx.x;
  const int wave = tid >> 6;
  const int lane = tid & 63;

  const float* px = xyz + (size_t)b * NPTS * 3;
  const float* pc = centroids + (size_t)gw * 3;
  const float cx = pc[0], cy = pc[1], cz = pc[2];
  // float32(0.04): numpy compares f32 sqd against python-double 0.04 demoted
  // to f32. NOT 0.2f*0.2f (that's a different float, 1 ulp larger).
  const float rr = 0.04f;

  __shared__ int sh_idx[KNBR];
  __shared__ float sh_gx[KNBR * 3];
  __shared__ unsigned long long sh_mask[4];

  int cnt = 0;  // uniform across all 256 threads by construction
  for (int n0 = 0; n0 < NPTS && cnt < KNBR; n0 += 256) {
    const int p = n0 + tid;
    const float xx = px[p * 3 + 0];
    const float yy = px[p * 3 + 1];
    const float zz = px[p * 3 + 2];
    const float dx = xx - cx;
    const float dy = yy - cy;
    const float dz = zz - cz;
    const float d = (dx * dx + dy * dy) + dz * dz;  // contract(off): no FMA
    const bool in = d <= rr;
    const unsigned long long mask = __ballot(in);
    if (lane == 0) sh_mask[wave] = mask;
    __syncthreads();
    const unsigned long long m0 = sh_mask[0];
    const unsigned long long m1 = sh_mask[1];
    const unsigned long long m2 = sh_mask[2];
    const unsigned long long m3 = sh_mask[3];
    int base = cnt;
    if (wave > 0) base += (int)__popcll(m0);
    if (wave > 1) base += (int)__popcll(m1);
    if (wave > 2) base += (int)__popcll(m2);
    const int pos = base + (int)__popcll(mask & ((1ull << lane) - 1ull));
    if (in && pos < KNBR) {
      sh_idx[pos] = p;
      sh_gx[pos * 3 + 0] = dx;
      sh_gx[pos * 3 + 1] = dy;
      sh_gx[pos * 3 + 2] = dz;
    }
    cnt += (int)(__popcll(m0) + __popcll(m1) + __popcll(m2) + __popcll(m3));
    __syncthreads();  // protect sh_mask reuse next super-chunk
  }
  if (cnt == 0 && tid == 0) {  // safety: cannot happen
    sh_idx[0] = 0;
    sh_gx[0] = px[0] - cx;
    sh_gx[1] = px[1] - cy;
    sh_gx[2] = px[2] - cz;
  }
  __syncthreads();

  const int nf0 = (cnt < 1) ? 1 : cnt;
  const int nf = (nf0 < KNBR) ? nf0 : KNBR;
  if (tid < KNBR && tid >= nf) {
    sh_idx[tid] = sh_idx[0];
    sh_gx[tid * 3 + 0] = sh_gx[0];
    sh_gx[tid * 3 + 1] = sh_gx[1];
    sh_gx[tid * 3 + 2] = sh_gx[2];
  }
  __syncthreads();

  float* ox = gxyz + (size_t)gw * KNBR * 3;
  if (tid < KNBR * 3) ox[tid] = sh_gx[tid];

  float* og = gfeat + (size_t)gw * KNBR * NCH;
  const float* pf = feat + (size_t)b * NPTS * NCH;
#pragma unroll
  for (int k = wave; k < KNBR; k += 4) {
    const int row = sh_idx[k];
    const float2 v = ((const float2*)(pf + (size_t)row * NCH))[lane];
    ((float2*)(og + (size_t)k * NCH))[lane] = v;
  }
}

extern "C" void kernel_launch(void* const* d_in, const int* in_sizes, int n_in,
                              void* d_out, int out_size, void* d_ws, size_t ws_size,
                              hipStream_t stream) {
  const float* xyz = (const float*)d_in[0];
  const float* feat = (const float*)d_in[1];
  float* out = (float*)d_out;
  const int B = in_sizes[0] / (NPTS * 3);

  float* centroids = out;                                   // [B,S,3]
  float* gxyz = centroids + (size_t)B * NSAMP * 3;          // [B,S,K,3]
  float* gfeat = gxyz + (size_t)B * NSAMP * KNBR * 3;       // [B,S,K,C]

  fps_kernel<<<B, FPS_TPB, 0, stream>>>(xyz, centroids);
  group_kernel<<<B * NSAMP, 256, 0, stream>>>(xyz, feat, centroids, gxyz,
                                              gfeat);
}